// Round 1
// baseline (342.988 us; speedup 1.0000x reference)
//
#include <hip/hip_runtime.h>
#include <hip/hip_bf16.h>
#include <math.h>

#define N_NODES 1024
#define KNN     16
#define CS      256
#define CZ      128
#define CG      16
#define NRBF    64
#define EPB     8

__device__ __forceinline__ float sigmoidf_(float x) {
    return 1.0f / (1.0f + __expf(-x));
}

// block reduce-sum over 128 threads (2 waves); result broadcast to all threads
__device__ __forceinline__ float block_sum_128(float v, float* red) {
    #pragma unroll
    for (int o = 32; o > 0; o >>= 1) v += __shfl_down(v, o);
    __syncthreads();                       // protect red[] from previous use
    if ((threadIdx.x & 63) == 0) red[threadIdx.x >> 6] = v;
    __syncthreads();
    return red[0] + red[1];
}

// ---------------- nl / nr projection: [N,256] @ [256,16] + b ----------------
__global__ __launch_bounds__(64) void nlr_kernel(
    const float* __restrict__ nf,
    const float* __restrict__ Wl, const float* __restrict__ bl,
    const float* __restrict__ Wr, const float* __restrict__ br,
    float* __restrict__ nl, float* __restrict__ nr) {
    int n = blockIdx.x;
    int t = threadIdx.x;
    if (t < 32) {
        int p = t & 15;
        const float* W = (t < 16) ? Wl : Wr;
        const float* b = (t < 16) ? bl : br;
        float acc = b[p];
        const float* row = nf + n * CS;
        for (int s = 0; s < CS; ++s) acc += row[s] * W[s * CG + p];
        float* dst = (t < 16) ? nl : nr;
        dst[n * CG + p] = acc;
    }
}

// -------- per-edge: z = LN(ef); e2 = sig(z@Weg+beg)*(z@Wep+bep); g = sig(z@Wog+bog)
__global__ __launch_bounds__(128) void edge_kernel(
    const float* __restrict__ ef,
    const float* __restrict__ ln_g, const float* __restrict__ ln_b,
    const float* __restrict__ Wep, const float* __restrict__ bep,
    const float* __restrict__ Weg, const float* __restrict__ beg,
    const float* __restrict__ Wog, const float* __restrict__ bog,
    float* __restrict__ e2o, float* __restrict__ go) {
    __shared__ __align__(16) float z[EPB][CZ];
    __shared__ float red[2];
    int c = threadIdx.x;
    int base = blockIdx.x * EPB;
    float lg = ln_g[c], lb = ln_b[c];
    for (int e = 0; e < EPB; ++e) {
        float x = ef[(base + e) * CZ + c];
        float s = block_sum_128(x, red);
        float m = s * (1.0f / CZ);
        float d = x - m;
        float v = block_sum_128(d * d, red) * (1.0f / CZ);
        z[e][c] = d * rsqrtf(v + 1e-5f) * lg + lb;
    }
    __syncthreads();
    float aep[EPB], aeg[EPB], aog[EPB];
    float bep_c = bep[c], beg_c = beg[c], bog_c = bog[c];
    #pragma unroll
    for (int e = 0; e < EPB; ++e) { aep[e] = bep_c; aeg[e] = beg_c; aog[e] = bog_c; }
    for (int i0 = 0; i0 < CZ; i0 += 4) {
        float4 zz[EPB];
        #pragma unroll
        for (int e = 0; e < EPB; ++e) zz[e] = *(const float4*)&z[e][i0];
        #pragma unroll
        for (int t = 0; t < 4; ++t) {
            float wep = Wep[(i0 + t) * CZ + c];
            float weg = Weg[(i0 + t) * CZ + c];
            float wog = Wog[(i0 + t) * CZ + c];
            #pragma unroll
            for (int e = 0; e < EPB; ++e) {
                float4 zv = zz[e];
                float zi = (t == 0) ? zv.x : (t == 1) ? zv.y : (t == 2) ? zv.z : zv.w;
                aep[e] += zi * wep;
                aeg[e] += zi * weg;
                aog[e] += zi * wog;
            }
        }
    }
    #pragma unroll
    for (int e = 0; e < EPB; ++e) {
        e2o[(base + e) * CZ + c] = sigmoidf_(aeg[e]) * aep[e];
        go[(base + e) * CZ + c]  = sigmoidf_(aog[e]);
    }
}

// ---------------- main: per (n,j) block, 128 threads (one channel each) -----
__global__ __launch_bounds__(128) void main_kernel(
    const float* __restrict__ trans,
    const float* __restrict__ nl, const float* __restrict__ nr,
    const float* __restrict__ Wdg, const float* __restrict__ bdg,
    const float* __restrict__ Wdp, const float* __restrict__ bdp,
    const float* __restrict__ e2, const float* __restrict__ gg,
    const float* __restrict__ lno_g, const float* __restrict__ lno_b,
    const float* __restrict__ Wout, const float* __restrict__ bout,
    const int* __restrict__ src, const int* __restrict__ resmask,
    float* __restrict__ out) {
    __shared__ __align__(16) float rbf[KNN][NRBF];
    __shared__ __align__(16) float hbuf[CZ];
    __shared__ float tk[KNN][4];
    __shared__ float km[KNN];
    __shared__ float ajs[KNN];
    __shared__ float bks[KNN][KNN];
    __shared__ float red[2];

    int n = blockIdx.x >> 4;
    int j = blockIdx.x & 15;
    int c = threadIdx.x;
    int ej = n * KNN + j;

    if (c < KNN) {
        int sk = src[n * KNN + c];
        km[c] = (resmask[sk] != 0 && resmask[n] != 0) ? 1.0f : 0.0f;
        tk[c][0] = trans[sk * 3 + 0];
        tk[c][1] = trans[sk * 3 + 1];
        tk[c][2] = trans[sk * 3 + 2];
        int sj = src[ej];
        ajs[c] = nl[sj * CG + c];
    }
    {
        int k = c >> 3, q = c & 7;
        int sk = src[n * KNN + k];
        bks[k][q]     = nr[sk * CG + q];
        bks[k][q + 8] = nr[sk * CG + q + 8];
    }
    __syncthreads();

    // rbf table: 16*64 values, 8 per thread
    #pragma unroll
    for (int i = 0; i < 8; ++i) {
        int idx = c + i * 128;
        int k = idx >> 6, r = idx & 63;
        float dx = tk[j][0] - tk[k][0] + 1e-8f;
        float dy = tk[j][1] - tk[k][1] + 1e-8f;
        float dz = tk[j][2] - tk[k][2] + 1e-8f;
        float d = sqrtf(dx * dx + dy * dy + dz * dz);
        float mu = (20.0f / 63.0f) * (float)r;
        float u = (d - mu) * (1.0f / 0.3125f);
        rbf[k][r] = __expf(-u * u);
    }

    // Wdp column for this channel into registers
    float wdp[NRBF];
    #pragma unroll
    for (int r = 0; r < NRBF; ++r) wdp[r] = Wdp[r * CZ + c];

    // av[q] = sum_p ajs[p] * Wdg[(p*16+q)*CZ + c]   (per-block j is fixed)
    float av[CG];
    #pragma unroll
    for (int q = 0; q < CG; ++q) av[q] = 0.0f;
    #pragma unroll
    for (int p = 0; p < CG; ++p) {
        float a = ajs[p];
        #pragma unroll
        for (int q = 0; q < CG; ++q) av[q] += a * Wdg[(p * CG + q) * CZ + c];
    }
    __syncthreads();   // rbf + bks + km ready

    float kmj = km[j];
    float bdp_c = bdp[c], bdg_c = bdg[c];
    float acc = 0.0f;
    for (int k = 0; k < KNN; ++k) {
        float df = bdp_c;
        const float4* rb4 = (const float4*)rbf[k];
        #pragma unroll
        for (int rv = 0; rv < NRBF / 4; ++rv) {
            float4 rb = rb4[rv];
            df += rb.x * wdp[4 * rv + 0] + rb.y * wdp[4 * rv + 1]
                + rb.z * wdp[4 * rv + 2] + rb.w * wdp[4 * rv + 3];
        }
        float gate = bdg_c;
        #pragma unroll
        for (int q = 0; q < CG; ++q) gate += bks[k][q] * av[q];
        float m2f = kmj * km[k];
        float e2v = e2[(n * KNN + k) * CZ + c];
        acc += sigmoidf_(gate) * df * m2f * e2v;
    }

    // LayerNorm over channels, then @Wout + bout, * g, * mask
    float s = block_sum_128(acc, red);
    float m = s * (1.0f / CZ);
    float d0 = acc - m;
    float v = block_sum_128(d0 * d0, red) * (1.0f / CZ);
    hbuf[c] = d0 * rsqrtf(v + 1e-5f) * lno_g[c] + lno_b[c];
    __syncthreads();

    float o = bout[c];
    for (int i0 = 0; i0 < CZ; i0 += 4) {
        float4 h = *(const float4*)&hbuf[i0];
        o += h.x * Wout[(i0 + 0) * CZ + c];
        o += h.y * Wout[(i0 + 1) * CZ + c];
        o += h.z * Wout[(i0 + 2) * CZ + c];
        o += h.w * Wout[(i0 + 3) * CZ + c];
    }
    o *= gg[ej * CZ + c];
    o *= kmj;
    out[ej * CZ + c] = o;
}

extern "C" void kernel_launch(void* const* d_in, const int* in_sizes, int n_in,
                              void* d_out, int out_size, void* d_ws, size_t ws_size,
                              hipStream_t stream) {
    const float* node_features = (const float*)d_in[0];
    const float* trans         = (const float*)d_in[1];
    const float* edge_features = (const float*)d_in[2];
    const float* ln_g  = (const float*)d_in[3];
    const float* ln_b  = (const float*)d_in[4];
    const float* Wl    = (const float*)d_in[5];
    const float* bl    = (const float*)d_in[6];
    const float* Wr    = (const float*)d_in[7];
    const float* br    = (const float*)d_in[8];
    const float* Wep   = (const float*)d_in[9];
    const float* bep   = (const float*)d_in[10];
    const float* Weg   = (const float*)d_in[11];
    const float* beg   = (const float*)d_in[12];
    const float* Wdg   = (const float*)d_in[13];
    const float* bdg   = (const float*)d_in[14];
    const float* Wdp   = (const float*)d_in[15];
    const float* bdp   = (const float*)d_in[16];
    const float* lno_g = (const float*)d_in[17];
    const float* lno_b = (const float*)d_in[18];
    const float* Wout  = (const float*)d_in[19];
    const float* bout  = (const float*)d_in[20];
    const float* Wog   = (const float*)d_in[21];
    const float* bog   = (const float*)d_in[22];
    const int* edge_index = (const int*)d_in[23];
    const int* resmask    = (const int*)d_in[25];

    float* ws = (float*)d_ws;
    float* nl = ws;
    float* nr = nl + N_NODES * CG;
    float* e2 = nr + N_NODES * CG;
    float* gg = e2 + N_NODES * KNN * CZ;
    const int* src = edge_index;   // row 0 of [2, N*K]

    nlr_kernel<<<N_NODES, 64, 0, stream>>>(node_features, Wl, bl, Wr, br, nl, nr);
    edge_kernel<<<(N_NODES * KNN) / EPB, 128, 0, stream>>>(
        edge_features, ln_g, ln_b, Wep, bep, Weg, beg, Wog, bog, e2, gg);
    main_kernel<<<N_NODES * KNN, 128, 0, stream>>>(
        trans, nl, nr, Wdg, bdg, Wdp, bdp, e2, gg, lno_g, lno_b,
        Wout, bout, src, resmask, (float*)d_out);
}

// Round 2
// 205.043 us; speedup vs baseline: 1.6728x; 1.6728x over previous
//
#include <hip/hip_runtime.h>
#include <hip/hip_bf16.h>
#include <math.h>

#define KNN  16
#define CZ   128
#define CG   16
#define CS   256
#define NRBF 64
#define NN   1024

typedef __attribute__((ext_vector_type(8))) short short8_t;
typedef __attribute__((ext_vector_type(4))) float f4_t;

#define MFMA_BF16(A, B, C) __builtin_amdgcn_mfma_f32_16x16x32_bf16((A), (B), (C), 0, 0, 0)

// pack two floats to bf16 pair (round-to-nearest-up via +0x8000)
__device__ __forceinline__ unsigned bpack(float x, float y) {
    unsigned a = __float_as_uint(x) + 0x8000u;
    unsigned b = __float_as_uint(y) + 0x8000u;
    return (a >> 16) | (b & 0xFFFF0000u);
}
__device__ __forceinline__ unsigned short b1pack(float x) {
    return (unsigned short)((__float_as_uint(x) + 0x8000u) >> 16);
}
__device__ __forceinline__ float sig_(float x) {
    return __builtin_amdgcn_rcpf(1.0f + __expf(-x));
}

// ---------------------------------------------------------------------------
// Repack fp32 weights [K][128] into MFMA 16x16x32 B-fragment layout, bf16:
// out[((s*8+ct)*64+lane)*8+t] = W[(s*32+(lane>>4)*8+t)*128 + ct*16+(lane&15)]
// Regions (bf16 elems): Wdp 8192 | Wdg 32768 | Wout 16384 | Wep/Weg/Wog 16384*3
// ---------------------------------------------------------------------------
__global__ __launch_bounds__(256) void repack_kernel(
    const float* __restrict__ Wdp, const float* __restrict__ Wdg,
    const float* __restrict__ Wout, const float* __restrict__ Wep,
    const float* __restrict__ Weg, const float* __restrict__ Wog,
    unsigned short* __restrict__ dst_base) {
    int gid = blockIdx.x * 256 + threadIdx.x;   // 0..106495
    const float* src;
    int o;
    if (gid < 8192)        { src = Wdp;  o = gid; }
    else if (gid < 40960)  { src = Wdg;  o = gid - 8192; }
    else if (gid < 57344)  { src = Wout; o = gid - 40960; }
    else if (gid < 73728)  { src = Wep;  o = gid - 57344; }
    else if (gid < 90112)  { src = Weg;  o = gid - 73728; }
    else                   { src = Wog;  o = gid - 90112; }
    int t  = o & 7;
    int l  = (o >> 3) & 63;
    int ct = (o >> 9) & 7;
    int s  = o >> 12;
    int row = s * 32 + (l >> 4) * 8 + t;
    int col = ct * 16 + (l & 15);
    dst_base[gid] = b1pack(src[row * CZ + col]);
}

// ---------------------------------------------------------------------------
// nl/nr projection: one wave per node. lane: p = lane&15, seg = lane>>4.
// ---------------------------------------------------------------------------
__global__ __launch_bounds__(64) void nlr_kernel(
    const float* __restrict__ nf,
    const float* __restrict__ Wl, const float* __restrict__ bl,
    const float* __restrict__ Wr, const float* __restrict__ br,
    float* __restrict__ nl, float* __restrict__ nr) {
    int n = blockIdx.x;
    int lane = threadIdx.x;
    int p = lane & 15, seg = lane >> 4;
    float accl = (seg == 0) ? bl[p] : 0.0f;
    float accr = (seg == 0) ? br[p] : 0.0f;
    const float* row = nf + n * CS + seg * 64;
    for (int i = 0; i < 64; ++i) {
        float v = row[i];
        int s = seg * 64 + i;
        accl += v * Wl[s * CG + p];
        accr += v * Wr[s * CG + p];
    }
    accl += __shfl_xor(accl, 16); accl += __shfl_xor(accl, 32);
    accr += __shfl_xor(accr, 16); accr += __shfl_xor(accr, 32);
    if (lane < 16) { nl[n * CG + lane] = accl; nr[n * CG + lane] = accr; }
}

// ---------------------------------------------------------------------------
// edge kernel: per block 64 edges, 4 waves, wave = one 16-row MFMA tile.
// LN(ef) -> z (bf16, LDS) -> 3 GEMMs vs Wep/Weg/Wog -> e2, gg (fp32 ws)
// ---------------------------------------------------------------------------
__global__ __launch_bounds__(256) void edge_kernel(
    const float* __restrict__ ef,
    const float* __restrict__ lng, const float* __restrict__ lnb,
    const float* __restrict__ bep, const float* __restrict__ beg,
    const float* __restrict__ bog,
    const unsigned short* __restrict__ Wepp,
    const unsigned short* __restrict__ Wegp,
    const unsigned short* __restrict__ Wogp,
    float* __restrict__ e2ws, float* __restrict__ ggws) {
    __shared__ unsigned short s_z[64 * 136];  // 64 rows, stride 136 bf16 (pad)
    __shared__ float s_lg[CZ], s_lb[CZ];
    int tid = threadIdx.x;
    if (tid < CZ) { s_lg[tid] = lng[tid]; s_lb[tid] = lnb[tid]; }
    __syncthreads();

    int wv = tid >> 6, lane = tid & 63, l15 = lane & 15, quad = lane >> 4;
    int base = blockIdx.x * 64;

    // --- LN phase: 4 lanes per edge, 32 cols each ---
    int eloc = wv * 16 + (lane >> 2);
    int col0 = (lane & 3) * 32;
    const float* row = ef + (size_t)(base + eloc) * CZ + col0;
    f4_t xv[8];
    #pragma unroll
    for (int i = 0; i < 8; ++i) xv[i] = *(const f4_t*)(row + i * 4);
    float s = 0.f, q = 0.f;
    #pragma unroll
    for (int i = 0; i < 8; ++i)
        #pragma unroll
        for (int r = 0; r < 4; ++r) { float v = xv[i][r]; s += v; q += v * v; }
    s += __shfl_xor(s, 1); s += __shfl_xor(s, 2);
    q += __shfl_xor(q, 1); q += __shfl_xor(q, 2);
    float mean = s * (1.0f / CZ);
    float var  = q * (1.0f / CZ) - mean * mean;
    float rs   = __builtin_amdgcn_rsqf(var + 1e-5f);
    #pragma unroll
    for (int i = 0; i < 8; ++i) {
        int c = col0 + i * 4;
        float z0 = (xv[i][0] - mean) * rs * s_lg[c + 0] + s_lb[c + 0];
        float z1 = (xv[i][1] - mean) * rs * s_lg[c + 1] + s_lb[c + 1];
        float z2 = (xv[i][2] - mean) * rs * s_lg[c + 2] + s_lb[c + 2];
        float z3 = (xv[i][3] - mean) * rs * s_lg[c + 3] + s_lb[c + 3];
        *(unsigned*)&s_z[eloc * 136 + c]     = bpack(z0, z1);
        *(unsigned*)&s_z[eloc * 136 + c + 2] = bpack(z2, z3);
    }
    // wave reads only its own 16 rows -> no __syncthreads needed

    // --- GEMM phase ---
    short8_t A[4];
    #pragma unroll
    for (int st = 0; st < 4; ++st)
        A[st] = *(const short8_t*)&s_z[(wv * 16 + l15) * 136 + st * 32 + quad * 8];

    for (int ct = 0; ct < 8; ++ct) {
        f4_t aep = {0.f, 0.f, 0.f, 0.f};
        f4_t aeg = {0.f, 0.f, 0.f, 0.f};
        f4_t aog = {0.f, 0.f, 0.f, 0.f};
        #pragma unroll
        for (int st = 0; st < 4; ++st) {
            int off = ((st * 8 + ct) * 64 + lane) * 8;
            short8_t bep_ = *(const short8_t*)(Wepp + off);
            short8_t beg_ = *(const short8_t*)(Wegp + off);
            short8_t bog_ = *(const short8_t*)(Wogp + off);
            aep = MFMA_BF16(A[st], bep_, aep);
            aeg = MFMA_BF16(A[st], beg_, aeg);
            aog = MFMA_BF16(A[st], bog_, aog);
        }
        int c = ct * 16 + l15;
        float vbep = bep[c], vbeg = beg[c], vbog = bog[c];
        #pragma unroll
        for (int r = 0; r < 4; ++r) {
            int e = base + wv * 16 + quad * 4 + r;
            float e2v = sig_(aeg[r] + vbeg) * (aep[r] + vbep);
            float ggv = sig_(aog[r] + vbog);
            e2ws[(size_t)e * CZ + c] = e2v;
            ggws[(size_t)e * CZ + c] = ggv;
        }
    }
}

// ---------------------------------------------------------------------------
// main kernel: one block per node (256 thr, 4 waves). Wave wv owns col-tiles
// {wv*2, wv*2+1} (32 channels) and loops all 16 j.
// ---------------------------------------------------------------------------
__global__ __launch_bounds__(256) void main_kernel(
    const float* __restrict__ trans,
    const float* __restrict__ nl, const float* __restrict__ nr,
    const unsigned short* __restrict__ Wdgp, const float* __restrict__ bdg,
    const unsigned short* __restrict__ Wdpp, const float* __restrict__ bdp,
    const float* __restrict__ e2ws, const float* __restrict__ ggws,
    const float* __restrict__ lnog, const float* __restrict__ lnob,
    const unsigned short* __restrict__ Woutp, const float* __restrict__ bout,
    const int* __restrict__ src, const int* __restrict__ resmask,
    float* __restrict__ out) {
    __shared__ float s_t[16 * 4];
    __shared__ float s_km[16];
    __shared__ int   s_src[16];
    __shared__ float s_a[16 * 16];
    __shared__ float s_b[16 * 20];          // padded stride 20
    __shared__ float s_upd[16 * CZ];
    __shared__ unsigned short s_uln[16 * 136];

    int n = blockIdx.x;
    int tid = threadIdx.x;
    if (tid < 16) {
        int sv = src[n * KNN + tid];
        s_src[tid] = sv;
        s_km[tid] = (resmask[sv] != 0 && resmask[n] != 0) ? 1.0f : 0.0f;
        s_t[tid * 4 + 0] = trans[sv * 3 + 0];
        s_t[tid * 4 + 1] = trans[sv * 3 + 1];
        s_t[tid * 4 + 2] = trans[sv * 3 + 2];
    }
    __syncthreads();
    {
        int j = tid >> 4, p = tid & 15;
        int sv = s_src[j];
        s_a[j * 16 + p] = nl[sv * CG + p];
        s_b[j * 20 + p] = nr[sv * CG + p];
    }
    __syncthreads();

    int wv = tid >> 6, lane = tid & 63, l15 = lane & 15, quad = lane >> 4;

    // persistent B fragments
    short8_t Bdg[8][2], Bdp[2][2];
    #pragma unroll
    for (int st = 0; st < 8; ++st)
        #pragma unroll
        for (int cc = 0; cc < 2; ++cc)
            Bdg[st][cc] = *(const short8_t*)(Wdgp + ((st * 8 + wv * 2 + cc) * 64 + lane) * 8);
    #pragma unroll
    for (int st = 0; st < 2; ++st)
        #pragma unroll
        for (int cc = 0; cc < 2; ++cc)
            Bdp[st][cc] = *(const short8_t*)(Wdpp + ((st * 8 + wv * 2 + cc) * 64 + lane) * 8);

    // j-invariant fragments: e2, km, biases
    f4_t e2f[2];
    float bdgv[2], bdpv[2];
    #pragma unroll
    for (int cc = 0; cc < 2; ++cc) {
        int c = (wv * 2 + cc) * 16 + l15;
        bdgv[cc] = bdg[c];
        bdpv[cc] = bdp[c];
        #pragma unroll
        for (int r = 0; r < 4; ++r)
            e2f[cc][r] = e2ws[(size_t)(n * KNN + quad * 4 + r) * CZ + c];
    }
    float kmf[4];
    #pragma unroll
    for (int r = 0; r < 4; ++r) kmf[r] = s_km[quad * 4 + r];

    float tkx = s_t[l15 * 4 + 0], tky = s_t[l15 * 4 + 1], tkz = s_t[l15 * 4 + 2];
    f4_t b0 = *(const f4_t*)&s_b[l15 * 20 + (quad & 1) * 8];
    f4_t b1 = *(const f4_t*)&s_b[l15 * 20 + (quad & 1) * 8 + 4];
    int ph = quad >> 1;
    const float MUS = 20.0f / 63.0f;
    const float ISG = 1.0f / 0.3125f;

    for (int j = 0; j < 16; ++j) {
        float dx = s_t[j * 4 + 0] - tkx + 1e-8f;
        float dy = s_t[j * 4 + 1] - tky + 1e-8f;
        float dz = s_t[j * 4 + 2] - tkz + 1e-8f;
        float d = sqrtf(dx * dx + dy * dy + dz * dz);

        // rbf A-fragments (rows = k = l15, K-dim = r)
        short8_t ar[2];
        #pragma unroll
        for (int st = 0; st < 2; ++st) {
            union { unsigned u[4]; short8_t v; } cv;
            float rbase = (float)(st * 32 + quad * 8);
            #pragma unroll
            for (int tt = 0; tt < 4; ++tt) {
                float mu0 = (rbase + (float)(2 * tt)) * MUS;
                float mu1 = mu0 + MUS;
                float u0 = (d - mu0) * ISG;
                float u1 = (d - mu1) * ISG;
                cv.u[tt] = bpack(__expf(-u0 * u0), __expf(-u1 * u1));
            }
            ar[st] = cv.v;
        }
        f4_t accd[2];
        #pragma unroll
        for (int cc = 0; cc < 2; ++cc) {
            f4_t z = {0.f, 0.f, 0.f, 0.f};
            z = MFMA_BF16(ar[0], Bdp[0][cc], z);
            z = MFMA_BF16(ar[1], Bdp[1][cc], z);
            accd[cc] = z;
        }

        // gate: E[k,pq] = a[j,p]*b[k,q], pq = p*16+q, 8 K-steps
        f4_t accg[2] = {{0.f, 0.f, 0.f, 0.f}, {0.f, 0.f, 0.f, 0.f}};
        #pragma unroll
        for (int st = 0; st < 8; ++st) {
            float a = s_a[j * 16 + st * 2 + ph];
            union { unsigned u[4]; short8_t v; } ev;
            ev.u[0] = bpack(a * b0[0], a * b0[1]);
            ev.u[1] = bpack(a * b0[2], a * b0[3]);
            ev.u[2] = bpack(a * b1[0], a * b1[1]);
            ev.u[3] = bpack(a * b1[2], a * b1[3]);
            accg[0] = MFMA_BF16(ev.v, Bdg[st][0], accg[0]);
            accg[1] = MFMA_BF16(ev.v, Bdg[st][1], accg[1]);
        }

        float kmj = s_km[j];
        #pragma unroll
        for (int cc = 0; cc < 2; ++cc) {
            float part = 0.f;
            #pragma unroll
            for (int r = 0; r < 4; ++r) {
                float e3 = sig_(accg[cc][r] + bdgv[cc]) * (accd[cc][r] + bdpv[cc])
                         * (kmj * kmf[r]);
                part += e3 * e2f[cc][r];
            }
            part += __shfl_xor(part, 16);
            part += __shfl_xor(part, 32);
            if (lane < 16) s_upd[j * CZ + (wv * 2 + cc) * 16 + lane] = part;
        }
    }
    __syncthreads();

    // LayerNorm rows wv*4 .. wv*4+3
    for (int rr = 0; rr < 4; ++rr) {
        int r = wv * 4 + rr;
        float x0 = s_upd[r * CZ + lane];
        float x1 = s_upd[r * CZ + 64 + lane];
        float sm = x0 + x1, sq = x0 * x0 + x1 * x1;
        #pragma unroll
        for (int m = 1; m < 64; m <<= 1) {
            sm += __shfl_xor(sm, m);
            sq += __shfl_xor(sq, m);
        }
        float mean = sm * (1.0f / CZ);
        float var  = sq * (1.0f / CZ) - mean * mean;
        float rsv  = __builtin_amdgcn_rsqf(var + 1e-5f);
        float h0 = (x0 - mean) * rsv * lnog[lane] + lnob[lane];
        float h1 = (x1 - mean) * rsv * lnog[64 + lane] + lnob[64 + lane];
        s_uln[r * 136 + lane]      = b1pack(h0);
        s_uln[r * 136 + 64 + lane] = b1pack(h1);
    }
    __syncthreads();

    // Wout GEMM: [16 j x 128] @ [128 x 128]
    short8_t Aw[4];
    #pragma unroll
    for (int st = 0; st < 4; ++st)
        Aw[st] = *(const short8_t*)&s_uln[l15 * 136 + st * 32 + quad * 8];
    #pragma unroll
    for (int cc = 0; cc < 2; ++cc) {
        f4_t acc = {0.f, 0.f, 0.f, 0.f};
        #pragma unroll
        for (int st = 0; st < 4; ++st) {
            short8_t bw = *(const short8_t*)(Woutp + ((st * 8 + wv * 2 + cc) * 64 + lane) * 8);
            acc = MFMA_BF16(Aw[st], bw, acc);
        }
        int c = (wv * 2 + cc) * 16 + l15;
        float bo = bout[c];
        #pragma unroll
        for (int r = 0; r < 4; ++r) {
            int row = quad * 4 + r;
            size_t oi = (size_t)(n * KNN + row) * CZ + c;
            float o = (acc[r] + bo) * ggws[oi] * s_km[row];
            out[oi] = o;
        }
    }
}

extern "C" void kernel_launch(void* const* d_in, const int* in_sizes, int n_in,
                              void* d_out, int out_size, void* d_ws, size_t ws_size,
                              hipStream_t stream) {
    const float* node_features = (const float*)d_in[0];
    const float* trans         = (const float*)d_in[1];
    const float* edge_features = (const float*)d_in[2];
    const float* ln_g  = (const float*)d_in[3];
    const float* ln_b  = (const float*)d_in[4];
    const float* Wl    = (const float*)d_in[5];
    const float* bl    = (const float*)d_in[6];
    const float* Wr    = (const float*)d_in[7];
    const float* br    = (const float*)d_in[8];
    const float* Wep   = (const float*)d_in[9];
    const float* bep   = (const float*)d_in[10];
    const float* Weg   = (const float*)d_in[11];
    const float* beg   = (const float*)d_in[12];
    const float* Wdg   = (const float*)d_in[13];
    const float* bdg   = (const float*)d_in[14];
    const float* Wdp   = (const float*)d_in[15];
    const float* bdp   = (const float*)d_in[16];
    const float* lno_g = (const float*)d_in[17];
    const float* lno_b = (const float*)d_in[18];
    const float* Wout  = (const float*)d_in[19];
    const float* bout  = (const float*)d_in[20];
    const float* Wog   = (const float*)d_in[21];
    const float* bog   = (const float*)d_in[22];
    const int* edge_index = (const int*)d_in[23];
    const int* resmask    = (const int*)d_in[25];

    float* ws = (float*)d_ws;
    float* nl   = ws;
    float* nr   = nl + NN * CG;
    float* e2ws = nr + NN * CG;
    float* ggws = e2ws + (size_t)NN * KNN * CZ;
    unsigned short* pk = (unsigned short*)(ggws + (size_t)NN * KNN * CZ);
    unsigned short* Wdpp  = pk;             // 8192
    unsigned short* Wdgp  = pk + 8192;      // 32768
    unsigned short* Woutp = pk + 40960;     // 16384
    unsigned short* Wepp  = pk + 57344;     // 16384
    unsigned short* Wegp  = pk + 73728;     // 16384
    unsigned short* Wogp  = pk + 90112;     // 16384
    const int* src = edge_index;            // row 0 of [2, N*K]

    repack_kernel<<<416, 256, 0, stream>>>(Wdp, Wdg, Wout, Wep, Weg, Wog, pk);
    nlr_kernel<<<NN, 64, 0, stream>>>(node_features, Wl, bl, Wr, br, nl, nr);
    edge_kernel<<<(NN * KNN) / 64, 256, 0, stream>>>(
        edge_features, ln_g, ln_b, bep, beg, bog, Wepp, Wegp, Wogp, e2ws, ggws);
    main_kernel<<<NN, 256, 0, stream>>>(
        trans, nl, nr, Wdgp, bdg, Wdpp, bdp, e2ws, ggws, lno_g, lno_b,
        Woutp, bout, src, resmask, (float*)d_out);
}

// Round 3
// 170.473 us; speedup vs baseline: 2.0120x; 1.2028x over previous
//
#include <hip/hip_runtime.h>
#include <hip/hip_bf16.h>
#include <math.h>

#define KNN  16
#define CZ   128
#define CG   16
#define CS   256
#define NRBF 64
#define NN   1024

typedef __attribute__((ext_vector_type(8))) _Float16 half8;
typedef __attribute__((ext_vector_type(2))) _Float16 half2v;
typedef __attribute__((ext_vector_type(4))) float f4_t;

#define MFMA_F16(A, B, C) __builtin_amdgcn_mfma_f32_16x16x32_f16((A), (B), (C), 0, 0, 0)

union U8 { half2v h[4]; half8 v; };

__device__ __forceinline__ half2v pk2(float x, float y) {
    auto t = __builtin_amdgcn_cvt_pkrtz(x, y);   // v_cvt_pkrtz_f16_f32
    half2v r;
    __builtin_memcpy(&r, &t, 4);
    return r;
}
__device__ __forceinline__ float sig_(float x) {
    return __builtin_amdgcn_rcpf(1.0f + __expf(-x));
}

// ---------------------------------------------------------------------------
// Repack fp32 weights [K][128] into MFMA 16x16x32 B-fragment layout, f16:
// out[((s*8+ct)*64+lane)*8+t] = W[(s*32+(lane>>4)*8+t)*128 + ct*16+(lane&15)]
// Regions (f16 elems): Wdp 8192 | Wdg 32768 | Wout 16384 | Wep/Weg/Wog 16384*3
// ---------------------------------------------------------------------------
__global__ __launch_bounds__(256) void repack_kernel(
    const float* __restrict__ Wdp, const float* __restrict__ Wdg,
    const float* __restrict__ Wout, const float* __restrict__ Wep,
    const float* __restrict__ Weg, const float* __restrict__ Wog,
    _Float16* __restrict__ dst_base) {
    int gid = blockIdx.x * 256 + threadIdx.x;   // 0..106495
    const float* src;
    int o;
    if (gid < 8192)        { src = Wdp;  o = gid; }
    else if (gid < 40960)  { src = Wdg;  o = gid - 8192; }
    else if (gid < 57344)  { src = Wout; o = gid - 40960; }
    else if (gid < 73728)  { src = Wep;  o = gid - 57344; }
    else if (gid < 90112)  { src = Weg;  o = gid - 73728; }
    else                   { src = Wog;  o = gid - 90112; }
    int t  = o & 7;
    int l  = (o >> 3) & 63;
    int ct = (o >> 9) & 7;
    int s  = o >> 12;
    int row = s * 32 + (l >> 4) * 8 + t;
    int col = ct * 16 + (l & 15);
    dst_base[gid] = (_Float16)src[row * CZ + col];
}

// ---------------------------------------------------------------------------
// nl/nr projection: one wave per node.
// ---------------------------------------------------------------------------
__global__ __launch_bounds__(64) void nlr_kernel(
    const float* __restrict__ nf,
    const float* __restrict__ Wl, const float* __restrict__ bl,
    const float* __restrict__ Wr, const float* __restrict__ br,
    float* __restrict__ nl, float* __restrict__ nr) {
    int n = blockIdx.x;
    int lane = threadIdx.x;
    int p = lane & 15, seg = lane >> 4;
    float accl = (seg == 0) ? bl[p] : 0.0f;
    float accr = (seg == 0) ? br[p] : 0.0f;
    const float* row = nf + n * CS + seg * 64;
    for (int i = 0; i < 64; ++i) {
        float v = row[i];
        int s = seg * 64 + i;
        accl += v * Wl[s * CG + p];
        accr += v * Wr[s * CG + p];
    }
    accl += __shfl_xor(accl, 16); accl += __shfl_xor(accl, 32);
    accr += __shfl_xor(accr, 16); accr += __shfl_xor(accr, 32);
    if (lane < 16) { nl[n * CG + lane] = accl; nr[n * CG + lane] = accr; }
}

// ---------------------------------------------------------------------------
// edge kernel: one block per node (16 edges). 4 waves; wave = 2 col-tiles,
// persistent B-frags. LN(ef)->z(f16 LDS)->3 GEMMs->e2 (pre-multiplied by
// km[k]), gg. 1024 blocks -> 16 waves/CU.
// ---------------------------------------------------------------------------
__global__ __launch_bounds__(256) void edge_kernel(
    const float* __restrict__ ef,
    const float* __restrict__ lng, const float* __restrict__ lnb,
    const float* __restrict__ bep, const float* __restrict__ beg,
    const float* __restrict__ bog,
    const _Float16* __restrict__ Wepp,
    const _Float16* __restrict__ Wegp,
    const _Float16* __restrict__ Wogp,
    const int* __restrict__ src, const int* __restrict__ resmask,
    float* __restrict__ e2ws, float* __restrict__ ggws) {
    __shared__ _Float16 s_z[16][136];
    __shared__ float s_km[16];
    int n = blockIdx.x;
    int tid = threadIdx.x;
    if (tid < 16) {
        int sv = src[n * KNN + tid];
        s_km[tid] = (resmask[sv] != 0 && resmask[n] != 0) ? 1.0f : 0.0f;
    }
    // --- LN: 16 lanes per row, 8 cols each ---
    int r = tid >> 4, seg = tid & 15;
    const float* row = ef + ((size_t)n * KNN + r) * CZ + seg * 8;
    f4_t x0 = *(const f4_t*)row;
    f4_t x1 = *(const f4_t*)(row + 4);
    float s = x0.x + x0.y + x0.z + x0.w + x1.x + x1.y + x1.z + x1.w;
    float q = x0.x * x0.x + x0.y * x0.y + x0.z * x0.z + x0.w * x0.w
            + x1.x * x1.x + x1.y * x1.y + x1.z * x1.z + x1.w * x1.w;
    #pragma unroll
    for (int m = 1; m < 16; m <<= 1) { s += __shfl_xor(s, m); q += __shfl_xor(q, m); }
    float mean = s * (1.0f / CZ);
    float var  = q * (1.0f / CZ) - mean * mean;
    float rs   = __builtin_amdgcn_rsqf(var + 1e-5f);
    int col = seg * 8;
    f4_t g0 = *(const f4_t*)(lng + col), g1 = *(const f4_t*)(lng + col + 4);
    f4_t b0 = *(const f4_t*)(lnb + col), b1 = *(const f4_t*)(lnb + col + 4);
    U8 zu;
    zu.h[0] = pk2((x0.x - mean) * rs * g0.x + b0.x, (x0.y - mean) * rs * g0.y + b0.y);
    zu.h[1] = pk2((x0.z - mean) * rs * g0.z + b0.z, (x0.w - mean) * rs * g0.w + b0.w);
    zu.h[2] = pk2((x1.x - mean) * rs * g1.x + b1.x, (x1.y - mean) * rs * g1.y + b1.y);
    zu.h[3] = pk2((x1.z - mean) * rs * g1.z + b1.z, (x1.w - mean) * rs * g1.w + b1.w);
    *(half8*)&s_z[r][col] = zu.v;
    __syncthreads();

    int wv = tid >> 6, lane = tid & 63, l15 = lane & 15, quad = lane >> 4;
    half8 A[4];
    #pragma unroll
    for (int st = 0; st < 4; ++st)
        A[st] = *(const half8*)&s_z[l15][st * 32 + quad * 8];

    #pragma unroll
    for (int cc = 0; cc < 2; ++cc) {
        int ct = wv * 2 + cc;
        int c = ct * 16 + l15;
        float vep = bep[c], veg = beg[c], vog = bog[c];
        f4_t aep = {vep, vep, vep, vep};
        f4_t aeg = {veg, veg, veg, veg};
        f4_t aog = {vog, vog, vog, vog};
        #pragma unroll
        for (int st = 0; st < 4; ++st) {
            int off = ((st * 8 + ct) * 64 + lane) * 8;
            half8 bep_ = *(const half8*)(Wepp + off);
            half8 beg_ = *(const half8*)(Wegp + off);
            half8 bog_ = *(const half8*)(Wogp + off);
            aep = MFMA_F16(A[st], bep_, aep);
            aeg = MFMA_F16(A[st], beg_, aeg);
            aog = MFMA_F16(A[st], bog_, aog);
        }
        #pragma unroll
        for (int rr = 0; rr < 4; ++rr) {
            int er = quad * 4 + rr;
            size_t idx = ((size_t)n * KNN + er) * CZ + c;
            e2ws[idx] = sig_(aeg[rr]) * aep[rr] * s_km[er];  // km[k] folded in
            ggws[idx] = sig_(aog[rr]);
        }
    }
}

// ---------------------------------------------------------------------------
// main kernel: one block per node (256 thr, 4 waves). Wave wv owns col-tiles
// {wv*2, wv*2+1} and loops all 16 j. f16 fragments + pk packing.
// ---------------------------------------------------------------------------
__global__ __launch_bounds__(256) void main_kernel(
    const float* __restrict__ trans,
    const float* __restrict__ nl, const float* __restrict__ nr,
    const _Float16* __restrict__ Wdgp, const float* __restrict__ bdg,
    const _Float16* __restrict__ Wdpp, const float* __restrict__ bdp,
    const float* __restrict__ e2ws, const float* __restrict__ ggws,
    const float* __restrict__ lnog, const float* __restrict__ lnob,
    const _Float16* __restrict__ Woutp, const float* __restrict__ bout,
    const int* __restrict__ src, const int* __restrict__ resmask,
    float* __restrict__ out) {
    __shared__ float s_t[16 * 4];
    __shared__ float s_km[16];
    __shared__ int   s_src[16];
    __shared__ half2v s_a2[256];
    __shared__ float s_b[16 * 20];          // padded stride 20
    __shared__ float s_upd[16 * CZ];
    __shared__ _Float16 s_uln[16 * 136];

    int n = blockIdx.x;
    int tid = threadIdx.x;
    if (tid < 16) {
        int sv = src[n * KNN + tid];
        s_src[tid] = sv;
        s_km[tid] = (resmask[sv] != 0 && resmask[n] != 0) ? 1.0f : 0.0f;
        s_t[tid * 4 + 0] = trans[sv * 3 + 0];
        s_t[tid * 4 + 1] = trans[sv * 3 + 1];
        s_t[tid * 4 + 2] = trans[sv * 3 + 2];
    }
    __syncthreads();
    {
        int j = tid >> 4, p = tid & 15;
        int sv = s_src[j];
        float a = nl[sv * CG + p];
        s_a2[j * 16 + p] = pk2(a, a);
        s_b[j * 20 + p] = nr[sv * CG + p];
    }
    __syncthreads();

    int wv = tid >> 6, lane = tid & 63, l15 = lane & 15, quad = lane >> 4;

    // persistent B fragments
    half8 Bdg[8][2], Bdp[2][2];
    #pragma unroll
    for (int st = 0; st < 8; ++st)
        #pragma unroll
        for (int cc = 0; cc < 2; ++cc)
            Bdg[st][cc] = *(const half8*)(Wdgp + ((st * 8 + wv * 2 + cc) * 64 + lane) * 8);
    #pragma unroll
    for (int st = 0; st < 2; ++st)
        #pragma unroll
        for (int cc = 0; cc < 2; ++cc)
            Bdp[st][cc] = *(const half8*)(Wdpp + ((st * 8 + wv * 2 + cc) * 64 + lane) * 8);

    // j-invariant: e2 (includes km[k]), biases
    f4_t e2f[2];
    float bdgv[2], bdpv[2];
    #pragma unroll
    for (int cc = 0; cc < 2; ++cc) {
        int c = (wv * 2 + cc) * 16 + l15;
        bdgv[cc] = bdg[c];
        bdpv[cc] = bdp[c];
        #pragma unroll
        for (int rr = 0; rr < 4; ++rr)
            e2f[cc][rr] = e2ws[(size_t)(n * KNN + quad * 4 + rr) * CZ + c];
    }

    float tkx = s_t[l15 * 4 + 0], tky = s_t[l15 * 4 + 1], tkz = s_t[l15 * 4 + 2];
    f4_t bv0 = *(const f4_t*)&s_b[l15 * 20 + (quad & 1) * 8];
    f4_t bv1 = *(const f4_t*)&s_b[l15 * 20 + (quad & 1) * 8 + 4];
    half2v bh[4];
    bh[0] = pk2(bv0.x, bv0.y);
    bh[1] = pk2(bv0.z, bv0.w);
    bh[2] = pk2(bv1.x, bv1.y);
    bh[3] = pk2(bv1.z, bv1.w);
    int ph = quad >> 1;
    const float MUS = 20.0f / 63.0f;
    const float ISG = 1.0f / 0.3125f;
    // precomputed per-st rbf constants (j-invariant)
    float rIS[2];
    #pragma unroll
    for (int st = 0; st < 2; ++st)
        rIS[st] = (float)(st * 32 + quad * 8) * (MUS * ISG);

    for (int j = 0; j < 16; ++j) {
        float dx = s_t[j * 4 + 0] - tkx + 1e-8f;
        float dy = s_t[j * 4 + 1] - tky + 1e-8f;
        float dz = s_t[j * 4 + 2] - tkz + 1e-8f;
        float dI = sqrtf(dx * dx + dy * dy + dz * dz) * ISG;

        // rbf A-fragments (rows = k = l15, K-dim = r)
        half8 ar[2];
        #pragma unroll
        for (int st = 0; st < 2; ++st) {
            U8 cv;
            float base0 = dI - rIS[st];
            #pragma unroll
            for (int tt = 0; tt < 4; ++tt) {
                float u0 = base0 - (float)(2 * tt) * (MUS * ISG);
                float u1 = u0 - (MUS * ISG);
                cv.h[tt] = pk2(__expf(-u0 * u0), __expf(-u1 * u1));
            }
            ar[st] = cv.v;
        }
        f4_t accd[2];
        #pragma unroll
        for (int cc = 0; cc < 2; ++cc) {
            f4_t z = {bdpv[cc], bdpv[cc], bdpv[cc], bdpv[cc]};
            z = MFMA_F16(ar[0], Bdp[0][cc], z);
            z = MFMA_F16(ar[1], Bdp[1][cc], z);
            accd[cc] = z;
        }

        // gate: E[k,pq] = a[j,p]*b[k,q] via v_pk_mul_f16
        f4_t accg[2];
        accg[0] = (f4_t){bdgv[0], bdgv[0], bdgv[0], bdgv[0]};
        accg[1] = (f4_t){bdgv[1], bdgv[1], bdgv[1], bdgv[1]};
        #pragma unroll
        for (int st = 0; st < 8; ++st) {
            half2v av = s_a2[j * 16 + st * 2 + ph];
            U8 ev;
            ev.h[0] = av * bh[0];
            ev.h[1] = av * bh[1];
            ev.h[2] = av * bh[2];
            ev.h[3] = av * bh[3];
            accg[0] = MFMA_F16(ev.v, Bdg[st][0], accg[0]);
            accg[1] = MFMA_F16(ev.v, Bdg[st][1], accg[1]);
        }

        float kmj = s_km[j];
        #pragma unroll
        for (int cc = 0; cc < 2; ++cc) {
            float part = 0.f;
            #pragma unroll
            for (int rr = 0; rr < 4; ++rr)
                part += sig_(accg[cc][rr]) * accd[cc][rr] * e2f[cc][rr];
            part += __shfl_xor(part, 16);
            part += __shfl_xor(part, 32);
            if (lane < 16) s_upd[j * CZ + (wv * 2 + cc) * 16 + lane] = part * kmj;
        }
    }
    __syncthreads();

    // LayerNorm rows wv*4 .. wv*4+3
    for (int rr = 0; rr < 4; ++rr) {
        int r = wv * 4 + rr;
        float x0 = s_upd[r * CZ + lane];
        float x1 = s_upd[r * CZ + 64 + lane];
        float sm = x0 + x1, sq = x0 * x0 + x1 * x1;
        #pragma unroll
        for (int m = 1; m < 64; m <<= 1) {
            sm += __shfl_xor(sm, m);
            sq += __shfl_xor(sq, m);
        }
        float mean = sm * (1.0f / CZ);
        float var  = sq * (1.0f / CZ) - mean * mean;
        float rsv  = __builtin_amdgcn_rsqf(var + 1e-5f);
        float h0 = (x0 - mean) * rsv * lnog[lane] + lnob[lane];
        float h1 = (x1 - mean) * rsv * lnog[64 + lane] + lnob[64 + lane];
        s_uln[r * 136 + lane]      = (_Float16)h0;
        s_uln[r * 136 + 64 + lane] = (_Float16)h1;
    }
    __syncthreads();

    // Wout GEMM: [16 j x 128] @ [128 x 128]
    half8 Aw[4];
    #pragma unroll
    for (int st = 0; st < 4; ++st)
        Aw[st] = *(const half8*)&s_uln[l15 * 136 + st * 32 + quad * 8];
    #pragma unroll
    for (int cc = 0; cc < 2; ++cc) {
        int c = (wv * 2 + cc) * 16 + l15;
        float bo = bout[c];
        f4_t acc = {bo, bo, bo, bo};
        #pragma unroll
        for (int st = 0; st < 4; ++st) {
            half8 bw = *(const half8*)(Woutp + ((st * 8 + wv * 2 + cc) * 64 + lane) * 8);
            acc = MFMA_F16(Aw[st], bw, acc);
        }
        #pragma unroll
        for (int rr = 0; rr < 4; ++rr) {
            int row = quad * 4 + rr;
            size_t oi = (size_t)(n * KNN + row) * CZ + c;
            out[oi] = acc[rr] * ggws[oi] * s_km[row];
        }
    }
}

extern "C" void kernel_launch(void* const* d_in, const int* in_sizes, int n_in,
                              void* d_out, int out_size, void* d_ws, size_t ws_size,
                              hipStream_t stream) {
    const float* node_features = (const float*)d_in[0];
    const float* trans         = (const float*)d_in[1];
    const float* edge_features = (const float*)d_in[2];
    const float* ln_g  = (const float*)d_in[3];
    const float* ln_b  = (const float*)d_in[4];
    const float* Wl    = (const float*)d_in[5];
    const float* bl    = (const float*)d_in[6];
    const float* Wr    = (const float*)d_in[7];
    const float* br    = (const float*)d_in[8];
    const float* Wep   = (const float*)d_in[9];
    const float* bep   = (const float*)d_in[10];
    const float* Weg   = (const float*)d_in[11];
    const float* beg   = (const float*)d_in[12];
    const float* Wdg   = (const float*)d_in[13];
    const float* bdg   = (const float*)d_in[14];
    const float* Wdp   = (const float*)d_in[15];
    const float* bdp   = (const float*)d_in[16];
    const float* lno_g = (const float*)d_in[17];
    const float* lno_b = (const float*)d_in[18];
    const float* Wout  = (const float*)d_in[19];
    const float* bout  = (const float*)d_in[20];
    const float* Wog   = (const float*)d_in[21];
    const float* bog   = (const float*)d_in[22];
    const int* edge_index = (const int*)d_in[23];
    const int* resmask    = (const int*)d_in[25];

    float* ws = (float*)d_ws;
    float* nl   = ws;
    float* nr   = nl + NN * CG;
    float* e2ws = nr + NN * CG;
    float* ggws = e2ws + (size_t)NN * KNN * CZ;
    _Float16* pk = (_Float16*)(ggws + (size_t)NN * KNN * CZ);
    _Float16* Wdpp  = pk;             // 8192
    _Float16* Wdgp  = pk + 8192;      // 32768
    _Float16* Woutp = pk + 40960;     // 16384
    _Float16* Wepp  = pk + 57344;     // 16384
    _Float16* Wegp  = pk + 73728;     // 16384
    _Float16* Wogp  = pk + 90112;     // 16384
    const int* src = edge_index;      // row 0 of [2, N*K]

    repack_kernel<<<416, 256, 0, stream>>>(Wdp, Wdg, Wout, Wep, Weg, Wog, pk);
    nlr_kernel<<<NN, 64, 0, stream>>>(node_features, Wl, bl, Wr, br, nl, nr);
    edge_kernel<<<NN, 256, 0, stream>>>(
        edge_features, ln_g, ln_b, bep, beg, bog, Wepp, Wegp, Wogp,
        src, resmask, e2ws, ggws);
    main_kernel<<<NN, 256, 0, stream>>>(
        trans, nl, nr, Wdgp, bdg, Wdpp, bdp, e2ws, ggws, lno_g, lno_b,
        Woutp, bout, src, resmask, (float*)d_out);
}

// Round 4
// 163.227 us; speedup vs baseline: 2.1013x; 1.0444x over previous
//
#include <hip/hip_runtime.h>
#include <hip/hip_bf16.h>
#include <math.h>

#define KNN  16
#define CZ   128
#define CG   16
#define CS   256
#define NRBF 64
#define NN   1024

typedef __attribute__((ext_vector_type(8))) _Float16 half8;
typedef __attribute__((ext_vector_type(4))) _Float16 half4;
typedef __attribute__((ext_vector_type(2))) _Float16 half2v;
typedef __attribute__((ext_vector_type(4))) float f4_t;

#define MFMA16x32(A, B, C) __builtin_amdgcn_mfma_f32_16x16x32_f16((A), (B), (C), 0, 0, 0)
#define MFMA16x16(A, B, C) __builtin_amdgcn_mfma_f32_16x16x16f16((A), (B), (C), 0, 0, 0)

union U8 { half2v h[4]; half8 v; };
union U4 { half2v h[2]; half4 v; };

__device__ __forceinline__ half2v pk2(float x, float y) {
    auto t = __builtin_amdgcn_cvt_pkrtz(x, y);
    half2v r;
    __builtin_memcpy(&r, &t, 4);
    return r;
}
__device__ __forceinline__ float sig_(float x) {
    return __builtin_amdgcn_rcpf(1.0f + __expf(-x));
}

// ---------------------------------------------------------------------------
// prep kernel: blocks [0,416) repack weights to f16 MFMA frag layouts;
// blocks [416,672) compute nl/nr (4 nodes per block, 1 wave each).
// pk regions (f16): Wdpp 8192 | Wdg2 32768 | Woutp 16384 | Wepp/Wegp/Wogp 16384*3
// Old layout (16x16x32 B-frag): out[((s*8+ct)*64+l)*8+t] = W[(s*32+(l>>4)*8+t)*CZ + ct*16+(l&15)]
// Wdg2 (16x16x16 B-frag per q): out[((q*8+ct)*64+l)*4+i] = Wdg[(4*(l>>4)+i)*16+q][ct*16+(l&15)]
// ---------------------------------------------------------------------------
__global__ __launch_bounds__(256) void prep_kernel(
    const float* __restrict__ Wdp, const float* __restrict__ Wdg,
    const float* __restrict__ Wout, const float* __restrict__ Wep,
    const float* __restrict__ Weg, const float* __restrict__ Wog,
    _Float16* __restrict__ pk,
    const float* __restrict__ nf,
    const float* __restrict__ Wl, const float* __restrict__ bl,
    const float* __restrict__ Wr, const float* __restrict__ br,
    float* __restrict__ nlo, float* __restrict__ nro) {
    int b = blockIdx.x, tid = threadIdx.x;
    if (b < 416) {
        int gid = b * 256 + tid;
        float val;
        if (gid >= 8192 && gid < 40960) {
            int o = gid - 8192;
            int i = o & 3, l = (o >> 2) & 63, ct = (o >> 8) & 7, q = o >> 11;
            int row = (4 * (l >> 4) + i) * 16 + q;
            int col = ct * 16 + (l & 15);
            val = Wdg[row * CZ + col];
        } else {
            const float* srcw;
            int o;
            if (gid < 8192)        { srcw = Wdp;  o = gid; }
            else if (gid < 57344)  { srcw = Wout; o = gid - 40960; }
            else if (gid < 73728)  { srcw = Wep;  o = gid - 57344; }
            else if (gid < 90112)  { srcw = Weg;  o = gid - 73728; }
            else                   { srcw = Wog;  o = gid - 90112; }
            int t = o & 7, l = (o >> 3) & 63, ct = (o >> 9) & 7, s = o >> 12;
            int row = s * 32 + (l >> 4) * 8 + t;
            int col = ct * 16 + (l & 15);
            val = srcw[row * CZ + col];
        }
        pk[gid] = (_Float16)val;
    } else {
        int grp = tid >> 6, lane = tid & 63;
        int n = (b - 416) * 4 + grp;
        int p = lane & 15, seg = lane >> 4;
        float accl = (seg == 0) ? bl[p] : 0.0f;
        float accr = (seg == 0) ? br[p] : 0.0f;
        const float* rw = nf + n * CS + seg * 64;
        for (int i = 0; i < 64; ++i) {
            float v = rw[i];
            int s = seg * 64 + i;
            accl += v * Wl[s * CG + p];
            accr += v * Wr[s * CG + p];
        }
        accl += __shfl_xor(accl, 16); accl += __shfl_xor(accl, 32);
        accr += __shfl_xor(accr, 16); accr += __shfl_xor(accr, 32);
        if (lane < 16) { nlo[n * CG + lane] = accl; nro[n * CG + lane] = accr; }
    }
}

// ---------------------------------------------------------------------------
// fused main kernel: one block per node, 256 threads (4 waves). Wave wv owns
// col-tiles {2wv, 2wv+1}. Phases:
//  1. LN(ef) -> s_z (f16)
//  2. 3 edge GEMMs -> e2f (with km[k] folded), ggf  [registers, stay resident]
//  3. step A': T[j,q,c] = a[j,:]@Wdg-slices  (wave-private LDS, f16)
//  4. j-loop: rbf frags -> df MFMA; gate = b @ T_j (1 mfma16x16x16 per ct);
//     sigmoid epilogue; Sum_k via shfl -> s_upd
//  5. LN rows + Wout GEMM + *ggf*km -> out
// ---------------------------------------------------------------------------
__global__ __launch_bounds__(256) void main_kernel(
    const float* __restrict__ trans, const float* __restrict__ ef,
    const float* __restrict__ lng, const float* __restrict__ lnb,
    const float* __restrict__ nl, const float* __restrict__ nr,
    const float* __restrict__ bep, const float* __restrict__ beg,
    const float* __restrict__ bog,
    const _Float16* __restrict__ Wepp, const _Float16* __restrict__ Wegp,
    const _Float16* __restrict__ Wogp,
    const _Float16* __restrict__ Wdg2, const float* __restrict__ bdg,
    const _Float16* __restrict__ Wdpp, const float* __restrict__ bdp,
    const float* __restrict__ lnog, const float* __restrict__ lnob,
    const _Float16* __restrict__ Woutp, const float* __restrict__ bout,
    const int* __restrict__ src, const int* __restrict__ resmask,
    float* __restrict__ out) {
    __shared__ _Float16 s_z[16 * 136];        // LN(ef); later aliased as uln
    __shared__ float s_t[16 * 4];
    __shared__ float s_km[16];
    __shared__ int   s_src[16];
    __shared__ float s_a[16 * 16];
    __shared__ float s_b[16 * 20];            // padded stride 20
    __shared__ _Float16 s_T[4][8192];         // per-wave T: [j][ctl][c16][q16]
    __shared__ _Float16 s_upd[16 * 136];      // f16 upd rows

    int n = blockIdx.x, tid = threadIdx.x;
    if (tid < 16) {
        int sv = src[n * KNN + tid];
        s_src[tid] = sv;
        s_km[tid] = (resmask[sv] != 0 && resmask[n] != 0) ? 1.0f : 0.0f;
        s_t[tid * 4 + 0] = trans[sv * 3 + 0];
        s_t[tid * 4 + 1] = trans[sv * 3 + 1];
        s_t[tid * 4 + 2] = trans[sv * 3 + 2];
    }
    __syncthreads();
    {
        int j = tid >> 4, p = tid & 15;
        int sv = s_src[j];
        s_a[j * 16 + p] = nl[sv * CG + p];
        s_b[j * 20 + p] = nr[sv * CG + p];
    }
    // --- phase 1: LN ---
    {
        int r = tid >> 4, seg = tid & 15;
        const float* row = ef + ((size_t)n * KNN + r) * CZ + seg * 8;
        f4_t x0 = *(const f4_t*)row;
        f4_t x1 = *(const f4_t*)(row + 4);
        float s = x0.x + x0.y + x0.z + x0.w + x1.x + x1.y + x1.z + x1.w;
        float q = x0.x * x0.x + x0.y * x0.y + x0.z * x0.z + x0.w * x0.w
                + x1.x * x1.x + x1.y * x1.y + x1.z * x1.z + x1.w * x1.w;
        #pragma unroll
        for (int m = 1; m < 16; m <<= 1) { s += __shfl_xor(s, m); q += __shfl_xor(q, m); }
        float mean = s * (1.0f / CZ);
        float var  = q * (1.0f / CZ) - mean * mean;
        float rs   = __builtin_amdgcn_rsqf(var + 1e-5f);
        int col = seg * 8;
        f4_t g0 = *(const f4_t*)(lng + col), g1 = *(const f4_t*)(lng + col + 4);
        f4_t b0 = *(const f4_t*)(lnb + col), b1 = *(const f4_t*)(lnb + col + 4);
        U8 zu;
        zu.h[0] = pk2((x0.x - mean) * rs * g0.x + b0.x, (x0.y - mean) * rs * g0.y + b0.y);
        zu.h[1] = pk2((x0.z - mean) * rs * g0.z + b0.z, (x0.w - mean) * rs * g0.w + b0.w);
        zu.h[2] = pk2((x1.x - mean) * rs * g1.x + b1.x, (x1.y - mean) * rs * g1.y + b1.y);
        zu.h[3] = pk2((x1.z - mean) * rs * g1.z + b1.z, (x1.w - mean) * rs * g1.w + b1.w);
        *(half8*)&s_z[r * 136 + col] = zu.v;
    }
    __syncthreads();

    int wv = tid >> 6, lane = tid & 63, l15 = lane & 15, quad = lane >> 4;

    // --- phase 2: edge GEMMs -> e2f, ggf in registers ---
    half8 Az[4];
    #pragma unroll
    for (int st = 0; st < 4; ++st)
        Az[st] = *(const half8*)&s_z[l15 * 136 + st * 32 + quad * 8];
    f4_t e2f[2], ggf[2];
    #pragma unroll
    for (int cc = 0; cc < 2; ++cc) {
        int ct = wv * 2 + cc;
        int c = ct * 16 + l15;
        float vep = bep[c], veg = beg[c], vog = bog[c];
        f4_t aep = {vep, vep, vep, vep};
        f4_t aeg = {veg, veg, veg, veg};
        f4_t aog = {vog, vog, vog, vog};
        #pragma unroll
        for (int st = 0; st < 4; ++st) {
            int off = ((st * 8 + ct) * 64 + lane) * 8;
            half8 wep_ = *(const half8*)(Wepp + off);
            half8 weg_ = *(const half8*)(Wegp + off);
            half8 wog_ = *(const half8*)(Wogp + off);
            aep = MFMA16x32(Az[st], wep_, aep);
            aeg = MFMA16x32(Az[st], weg_, aeg);
            aog = MFMA16x32(Az[st], wog_, aog);
        }
        #pragma unroll
        for (int rr = 0; rr < 4; ++rr) {
            e2f[cc][rr] = sig_(aeg[rr]) * aep[rr] * s_km[quad * 4 + rr];
            ggf[cc][rr] = sig_(aog[rr]);
        }
    }

    // persistent Wdp B-frags
    half8 Bdp[2][2];
    #pragma unroll
    for (int st = 0; st < 2; ++st)
        #pragma unroll
        for (int cc = 0; cc < 2; ++cc)
            Bdp[st][cc] = *(const half8*)(Wdpp + ((st * 8 + wv * 2 + cc) * 64 + lane) * 8);

    // --- phase 3: step A' -> T (wave-private) ---
    half4 Aa, Ab;
    {
        f4_t av = *(const f4_t*)&s_a[l15 * 16 + 4 * quad];
        U4 u; u.h[0] = pk2(av.x, av.y); u.h[1] = pk2(av.z, av.w);
        Aa = u.v;
        f4_t bv = *(const f4_t*)&s_b[l15 * 20 + 4 * quad];
        U4 w; w.h[0] = pk2(bv.x, bv.y); w.h[1] = pk2(bv.z, bv.w);
        Ab = w.v;
    }
    _Float16* Tw = s_T[wv];
    #pragma unroll
    for (int ctl = 0; ctl < 2; ++ctl) {
        int ct = wv * 2 + ctl;
        #pragma unroll
        for (int q0 = 0; q0 < 16; q0 += 4) {
            f4_t tq[4];
            #pragma unroll
            for (int qq = 0; qq < 4; ++qq) {
                half4 Bw = *(const half4*)(Wdg2 + (((q0 + qq) * 8 + ct) * 64 + lane) * 4);
                f4_t z = {0.f, 0.f, 0.f, 0.f};
                tq[qq] = MFMA16x16(Aa, Bw, z);
            }
            #pragma unroll
            for (int rr = 0; rr < 4; ++rr) {
                U4 u;
                u.h[0] = pk2(tq[0][rr], tq[1][rr]);
                u.h[1] = pk2(tq[2][rr], tq[3][rr]);
                *(half4*)&Tw[(((4 * quad + rr) * 2 + ctl) * 16 + l15) * 16 + q0] = u.v;
            }
        }
    }

    // --- phase 4: j-loop ---
    float bdgv[2], bdpv[2];
    #pragma unroll
    for (int cc = 0; cc < 2; ++cc) {
        int c = (wv * 2 + cc) * 16 + l15;
        bdgv[cc] = bdg[c];
        bdpv[cc] = bdp[c];
    }
    float tkx = s_t[l15 * 4 + 0], tky = s_t[l15 * 4 + 1], tkz = s_t[l15 * 4 + 2];
    const float MUS = 20.0f / 63.0f;
    const float ISG = 1.0f / 0.3125f;
    float rIS[2];
    #pragma unroll
    for (int st = 0; st < 2; ++st)
        rIS[st] = (float)(st * 32 + quad * 8) * (MUS * ISG);

    for (int j = 0; j < 16; ++j) {
        float dx = s_t[j * 4 + 0] - tkx + 1e-8f;
        float dy = s_t[j * 4 + 1] - tky + 1e-8f;
        float dz = s_t[j * 4 + 2] - tkz + 1e-8f;
        float dI = sqrtf(dx * dx + dy * dy + dz * dz) * ISG;

        half8 ar[2];
        #pragma unroll
        for (int st = 0; st < 2; ++st) {
            U8 cv;
            float base0 = dI - rIS[st];
            #pragma unroll
            for (int tt = 0; tt < 4; ++tt) {
                float u0 = base0 - (float)(2 * tt) * (MUS * ISG);
                float u1 = u0 - (MUS * ISG);
                cv.h[tt] = pk2(__expf(-u0 * u0), __expf(-u1 * u1));
            }
            ar[st] = cv.v;
        }
        f4_t accd[2], accg[2];
        #pragma unroll
        for (int cc = 0; cc < 2; ++cc) {
            f4_t z = {bdpv[cc], bdpv[cc], bdpv[cc], bdpv[cc]};
            z = MFMA16x32(ar[0], Bdp[0][cc], z);
            z = MFMA16x32(ar[1], Bdp[1][cc], z);
            accd[cc] = z;
            half4 Bt = *(const half4*)&Tw[((j * 2 + cc) * 16 + l15) * 16 + 4 * quad];
            f4_t g = {bdgv[cc], bdgv[cc], bdgv[cc], bdgv[cc]};
            accg[cc] = MFMA16x16(Ab, Bt, g);
        }
        float kmj = s_km[j];
        #pragma unroll
        for (int cc = 0; cc < 2; ++cc) {
            float part = 0.f;
            #pragma unroll
            for (int rr = 0; rr < 4; ++rr)
                part += sig_(accg[cc][rr]) * accd[cc][rr] * e2f[cc][rr];
            part += __shfl_xor(part, 16);
            part += __shfl_xor(part, 32);
            if (lane < 16)
                s_upd[j * 136 + (wv * 2 + cc) * 16 + lane] = (_Float16)(part * kmj);
        }
    }
    __syncthreads();

    // --- phase 5: LN rows + Wout ---
    #pragma unroll
    for (int rr2 = 0; rr2 < 4; ++rr2) {
        int rj = wv * 4 + rr2;
        float x0 = (float)s_upd[rj * 136 + lane];
        float x1 = (float)s_upd[rj * 136 + 64 + lane];
        float sm = x0 + x1, sq = x0 * x0 + x1 * x1;
        #pragma unroll
        for (int m = 1; m < 64; m <<= 1) {
            sm += __shfl_xor(sm, m);
            sq += __shfl_xor(sq, m);
        }
        float mean = sm * (1.0f / CZ);
        float var  = sq * (1.0f / CZ) - mean * mean;
        float rsv  = __builtin_amdgcn_rsqf(var + 1e-5f);
        float h0 = (x0 - mean) * rsv * lnog[lane] + lnob[lane];
        float h1 = (x1 - mean) * rsv * lnog[64 + lane] + lnob[64 + lane];
        s_z[rj * 136 + lane]      = (_Float16)h0;   // s_z reused as uln
        s_z[rj * 136 + 64 + lane] = (_Float16)h1;
    }
    __syncthreads();

    half8 Aw[4];
    #pragma unroll
    for (int st = 0; st < 4; ++st)
        Aw[st] = *(const half8*)&s_z[l15 * 136 + st * 32 + quad * 8];
    #pragma unroll
    for (int cc = 0; cc < 2; ++cc) {
        int c = (wv * 2 + cc) * 16 + l15;
        float bo = bout[c];
        f4_t acc = {bo, bo, bo, bo};
        #pragma unroll
        for (int st = 0; st < 4; ++st) {
            half8 bw = *(const half8*)(Woutp + ((st * 8 + wv * 2 + cc) * 64 + lane) * 8);
            acc = MFMA16x32(Aw[st], bw, acc);
        }
        #pragma unroll
        for (int rr = 0; rr < 4; ++rr) {
            int row = quad * 4 + rr;
            size_t oi = (size_t)(n * KNN + row) * CZ + c;
            out[oi] = acc[rr] * ggf[cc][rr] * s_km[row];
        }
    }
}

extern "C" void kernel_launch(void* const* d_in, const int* in_sizes, int n_in,
                              void* d_out, int out_size, void* d_ws, size_t ws_size,
                              hipStream_t stream) {
    const float* node_features = (const float*)d_in[0];
    const float* trans         = (const float*)d_in[1];
    const float* edge_features = (const float*)d_in[2];
    const float* ln_g  = (const float*)d_in[3];
    const float* ln_b  = (const float*)d_in[4];
    const float* Wl    = (const float*)d_in[5];
    const float* bl    = (const float*)d_in[6];
    const float* Wr    = (const float*)d_in[7];
    const float* br    = (const float*)d_in[8];
    const float* Wep   = (const float*)d_in[9];
    const float* bep   = (const float*)d_in[10];
    const float* Weg   = (const float*)d_in[11];
    const float* beg   = (const float*)d_in[12];
    const float* Wdg   = (const float*)d_in[13];
    const float* bdg   = (const float*)d_in[14];
    const float* Wdp   = (const float*)d_in[15];
    const float* bdp   = (const float*)d_in[16];
    const float* lno_g = (const float*)d_in[17];
    const float* lno_b = (const float*)d_in[18];
    const float* Wout  = (const float*)d_in[19];
    const float* bout  = (const float*)d_in[20];
    const float* Wog   = (const float*)d_in[21];
    const float* bog   = (const float*)d_in[22];
    const int* edge_index = (const int*)d_in[23];
    const int* resmask    = (const int*)d_in[25];

    float* ws = (float*)d_ws;
    float* nl = ws;
    float* nr = nl + NN * CG;
    _Float16* pk = (_Float16*)(nr + NN * CG);
    _Float16* Wdpp  = pk;             // 8192
    _Float16* Wdg2  = pk + 8192;      // 32768
    _Float16* Woutp = pk + 40960;     // 16384
    _Float16* Wepp  = pk + 57344;     // 16384
    _Float16* Wegp  = pk + 73728;     // 16384
    _Float16* Wogp  = pk + 90112;     // 16384
    const int* src = edge_index;      // row 0 of [2, N*K]

    prep_kernel<<<672, 256, 0, stream>>>(
        Wdp, Wdg, Wout, Wep, Weg, Wog, pk,
        node_features, Wl, bl, Wr, br, nl, nr);
    main_kernel<<<NN, 256, 0, stream>>>(
        trans, edge_features, ln_g, ln_b, nl, nr,
        bep, beg, bog, Wepp, Wegp, Wogp,
        Wdg2, bdg, Wdpp, bdp, lno_g, lno_b,
        Woutp, bout, src, resmask, (float*)d_out);
}